// Round 15
// baseline (305.622 us; speedup 1.0000x reference)
//
#include <hip/hip_runtime.h>
#include <cstdint>
#include <cstddef>

#define B_ 2
#define S_ 2048
#define D_ 2048
#define H_ 32
#define KV_ 8
#define HD_ 64
#define M_ (B_*S_)      // 4096 rows total
#define EQ_ (H_*HD_)    // 2048
#define EK_ (KV_*HD_)   // 512

typedef unsigned short u16;
typedef __attribute__((ext_vector_type(8))) short s16x8;   // 8 x bf16 (4 VGPRs)
typedef __attribute__((ext_vector_type(4))) float f32x4;

// q pre-scale folds 1/sqrt(HD)=0.125 and log2(e) so flash uses raw 2^x
#define QSCALE 0.18033688011112042f      // 0.125 * log2(e)
#define EXPOFF 15.869645449778564f       // 11 * log2(e)

#if __has_builtin(__builtin_amdgcn_exp2f)
#define EXP2(x) __builtin_amdgcn_exp2f(x)
#else
#define EXP2(x) __expf((x) * 0.6931471805599453f)
#endif

__device__ __forceinline__ u16 f2bf(float f) {
  unsigned u = __float_as_uint(f);
  u += 0x7fffu + ((u >> 16) & 1u);        // RNE
  return (u16)(u >> 16);
}
// pack two floats to two bf16 in one dword via v_perm (proven path)
__device__ __forceinline__ unsigned pk2(float a, float b) {
  unsigned ua = __float_as_uint(a) + 0x8000u;
  unsigned ub = __float_as_uint(b) + 0x8000u;
  return __builtin_amdgcn_perm(ub, ua, 0x07060302);  // lo16=bf16(a), hi16=bf16(b)
}
__device__ __forceinline__ f32x4 mfma16(s16x8 a, s16x8 b, f32x4 c) {
  return __builtin_amdgcn_mfma_f32_16x16x32_bf16(a, b, c, 0, 0, 0);
}
__device__ __forceinline__ void gl_lds16(const void* g, void* l) {
  __builtin_amdgcn_global_load_lds(
      (const __attribute__((address_space(1))) void*)g,
      (__attribute__((address_space(3))) void*)l, 16, 0, 0);
}

// ---------------- fused fp32 -> bf16 cast of all 5 inputs ----------------
// Grid-stride (G11): 2048 blocks x 256 threads x 9 iters = 4718592 exact.
__global__ void cast_all(const float4* __restrict__ x, const float4* __restrict__ wq,
                         const float4* __restrict__ wk, const float4* __restrict__ wv,
                         const float4* __restrict__ wo, ushort4* __restrict__ dst) {
  for (int i = blockIdx.x * 256 + threadIdx.x; i < 4718592; i += 524288) {
    const float4* src; int off;
    if (i < 2097152)      { src = x;  off = i; }
    else if (i < 3145728) { src = wq; off = i - 2097152; }
    else if (i < 3407872) { src = wk; off = i - 3145728; }
    else if (i < 3670016) { src = wv; off = i - 3407872; }
    else                  { src = wo; off = i - 3670016; }
    float4 v = src[off];
    ushort4 r;
    r.x = f2bf(v.x); r.y = f2bf(v.y); r.z = f2bf(v.z); r.w = f2bf(v.w);
    dst[i] = r;
  }
}

// ---------------- fused QKV projection GEMM v5: phase-split counted-vmcnt ----------------
// 128x96 tile (wave layout + epilogue identical to proven v2), BK=64 dbuf
// (56 KB LDS, grid 1024 = 2 blocks/CU x 2 passes exact). Each K-tile = 2
// phases; per phase: {s_waitcnt vmcnt(N); s_barrier; issue next-tile load
// group(s); ds_read; 12 MFMA}. N = 2 (p0) / 5 (p1) steady-state — loads for
// tile kt+1 stay in flight across barriers; NO vmcnt(0) drain in the loop
// (the m233 2-phase stall this removes was ~50% of kernel time).
// Load groups per tile per thread (uniform): G0 = B x3, G1 = A-half0 x2,
// G2 = A-half1 x2. A rows stored bit-5<->6-swapped (bitswap involution) so
// phase p consumes staged-slot prefix: slots[0-63] = rows {0-31,64-95}
// (= all waves' mi 0-1 rows), slots[64-127] = rows {32-63,96-127} (mi 2-3).
// Swizzle: 128-B rows, 8 chunks, phys = chunk ^ (row&7) (2-way free, both
// sides; slot&7 == row&7 since bitswap keeps bits 0-4).
// Cross-tile WAR (kt+1's issues write buf[kt&1]): issues happen after the
// (kt+1)-p0 barrier, which every wave reaches only after issuing its tile-kt
// reads; DMA flight time (>=200cy) >> LDS-read completion. [risk noted]
__global__ __launch_bounds__(256)
void gemm_qkv(const u16* __restrict__ A, const u16* __restrict__ Bw,
              u16* __restrict__ qb, u16* __restrict__ kb, u16* __restrict__ vtb,
              const float* __restrict__ fc) {
  __shared__ __align__(16) u16 As[2][128 * 64];   // 2 x 16 KB
  __shared__ __align__(16) u16 Bs[2][96 * 64];    // 2 x 12 KB
  const int tid  = threadIdx.x;
  const int lane = tid & 63;
  const int wave = tid >> 6;
  const int m0 = blockIdx.y * 128;
  const int n0 = blockIdx.x * 96;
  const int wm = (wave >> 1) * 64;
  const int wn = (wave & 1) * 48;
  const int l15 = lane & 15;
  const int quad = lane >> 4;

  // ---- staging geometry ----
  const int srow = tid >> 3;        // 0..31 (slot-row within a 32-row group)
  const int pos  = tid & 7;         // 16B chunk position within a 128B row
  const int scol = (pos ^ (srow & 7)) * 8;   // swizzled source k-offset (elems)

  // A loads g=0..3: LDS slot-row = g*32+srow; global row = bitswap(slot)
  // bitswap(x) = (x&31) | ((x&32)<<1) | ((x&64)>>1)  (swap bits 5,6)
  const u16* Ap[4];
  #pragma unroll
  for (int g = 0; g < 4; ++g) {
    int slot = g * 32 + srow;
    int r = (slot & 31) | ((slot & 32) << 1) | ((slot & 64) >> 1);
    Ap[g] = A + (size_t)(m0 + r) * D_ + scol;
  }
  const int da0 = (0 * 256 + tid) * 8, da1 = (1 * 256 + tid) * 8;
  const int da2 = (2 * 256 + tid) * 8, da3 = (3 * 256 + tid) * 8;
  // B loads h=0..2: row = h*32+srow (linear)
  const u16* Bp[3];
  #pragma unroll
  for (int h = 0; h < 3; ++h)
    Bp[h] = Bw + (size_t)(n0 + h * 32 + srow) * D_ + scol;
  const int db0 = (0 * 256 + tid) * 8, db1 = (1 * 256 + tid) * 8;
  const int db2 = (2 * 256 + tid) * 8;

  f32x4 acc[4][3] = {};

  // ---- prologue: stage tile 0 into buf 0 (order: B0,B1,B2,A0,A1,A2,A3) ----
  gl_lds16(Bp[0], &Bs[0][db0]); gl_lds16(Bp[1], &Bs[0][db1]); gl_lds16(Bp[2], &Bs[0][db2]);
  gl_lds16(Ap[0], &As[0][da0]); gl_lds16(Ap[1], &As[0][da1]);
  gl_lds16(Ap[2], &As[0][da2]); gl_lds16(Ap[3], &As[0][da3]);

  // fragment address helpers (compile-time mi/ni/kc; slot&7 == row&7)
  #define AFRAG(as_, mi_, kc_) \
    (*(const s16x8*)&(as_)[(((wm + (mi_)*16 + l15) & 31) | (((wm + (mi_)*16 + l15) & 32) << 1) | (((wm + (mi_)*16 + l15) & 64) >> 1)) * 64 + ((((kc_)*4 + quad) ^ ((wm + (mi_)*16 + l15) & 7)) * 8)])
  #define BFRAG(bs_, ni_, kc_) \
    (*(const s16x8*)&(bs_)[(wn + (ni_)*16 + l15) * 64 + ((((kc_)*4 + quad) ^ ((wn + (ni_)*16 + l15) & 7)) * 8)])

  for (int kt = 0; kt < 31; ++kt) {
    const u16* as = &As[kt & 1][0];
    const u16* bs = &Bs[kt & 1][0];
    u16* asn = &As[(kt + 1) & 1][0];
    u16* bsn = &Bs[(kt + 1) & 1][0];
    const int ko = (kt + 1) * 64;

    // ---- phase 0: needs B(kt)+A-half0(kt) = oldest 5 of 7 -> vmcnt(2) ----
    asm volatile("s_waitcnt vmcnt(2)" ::: "memory");
    __builtin_amdgcn_s_barrier();
    gl_lds16(Bp[0] + ko, bsn + db0); gl_lds16(Bp[1] + ko, bsn + db1); gl_lds16(Bp[2] + ko, bsn + db2);
    gl_lds16(Ap[0] + ko, asn + da0); gl_lds16(Ap[1] + ko, asn + da1);

    s16x8 bf[2][3];
    #pragma unroll
    for (int kc = 0; kc < 2; ++kc) {
      bf[kc][0] = BFRAG(bs, 0, kc); bf[kc][1] = BFRAG(bs, 1, kc); bf[kc][2] = BFRAG(bs, 2, kc);
    }
    {
      s16x8 a00 = AFRAG(as, 0, 0), a01 = AFRAG(as, 0, 1);
      s16x8 a10 = AFRAG(as, 1, 0), a11 = AFRAG(as, 1, 1);
      __builtin_amdgcn_s_setprio(1);
      #pragma unroll
      for (int ni = 0; ni < 3; ++ni) {
        acc[0][ni] = mfma16(a01, bf[1][ni], mfma16(a00, bf[0][ni], acc[0][ni]));
        acc[1][ni] = mfma16(a11, bf[1][ni], mfma16(a10, bf[0][ni], acc[1][ni]));
      }
      __builtin_amdgcn_s_setprio(0);
    }

    // ---- phase 1: needs A-half1(kt) = oldest 2 of 7 -> vmcnt(5) ----
    asm volatile("s_waitcnt vmcnt(5)" ::: "memory");
    __builtin_amdgcn_s_barrier();
    gl_lds16(Ap[2] + ko, asn + da2); gl_lds16(Ap[3] + ko, asn + da3);
    {
      s16x8 a20 = AFRAG(as, 2, 0), a21 = AFRAG(as, 2, 1);
      s16x8 a30 = AFRAG(as, 3, 0), a31 = AFRAG(as, 3, 1);
      __builtin_amdgcn_s_setprio(1);
      #pragma unroll
      for (int ni = 0; ni < 3; ++ni) {
        acc[2][ni] = mfma16(a21, bf[1][ni], mfma16(a20, bf[0][ni], acc[2][ni]));
        acc[3][ni] = mfma16(a31, bf[1][ni], mfma16(a30, bf[0][ni], acc[3][ni]));
      }
      __builtin_amdgcn_s_setprio(0);
    }
  }

  // ---- peeled last tile (kt = 31, buf 1; no issues -> waits {2, 0}) ----
  {
    const u16* as = &As[1][0];
    const u16* bs = &Bs[1][0];
    asm volatile("s_waitcnt vmcnt(2)" ::: "memory");
    __builtin_amdgcn_s_barrier();
    s16x8 bf[2][3];
    #pragma unroll
    for (int kc = 0; kc < 2; ++kc) {
      bf[kc][0] = BFRAG(bs, 0, kc); bf[kc][1] = BFRAG(bs, 1, kc); bf[kc][2] = BFRAG(bs, 2, kc);
    }
    {
      s16x8 a00 = AFRAG(as, 0, 0), a01 = AFRAG(as, 0, 1);
      s16x8 a10 = AFRAG(as, 1, 0), a11 = AFRAG(as, 1, 1);
      #pragma unroll
      for (int ni = 0; ni < 3; ++ni) {
        acc[0][ni] = mfma16(a01, bf[1][ni], mfma16(a00, bf[0][ni], acc[0][ni]));
        acc[1][ni] = mfma16(a11, bf[1][ni], mfma16(a10, bf[0][ni], acc[1][ni]));
      }
    }
    asm volatile("s_waitcnt vmcnt(0)" ::: "memory");
    __builtin_amdgcn_s_barrier();
    {
      s16x8 a20 = AFRAG(as, 2, 0), a21 = AFRAG(as, 2, 1);
      s16x8 a30 = AFRAG(as, 3, 0), a31 = AFRAG(as, 3, 1);
      #pragma unroll
      for (int ni = 0; ni < 3; ++ni) {
        acc[2][ni] = mfma16(a21, bf[1][ni], mfma16(a20, bf[0][ni], acc[2][ni]));
        acc[3][ni] = mfma16(a31, bf[1][ni], mfma16(a30, bf[0][ni], acc[3][ni]));
      }
    }
  }
  #undef AFRAG
  #undef BFRAG

  // ---- epilogue: per-ni region branch (wave-uniform; byte-identical to v2) ----
  const float sg = (l15 & 1) ? 1.f : -1.f;
  #pragma unroll
  for (int mi = 0; mi < 4; ++mi) {
    #pragma unroll
    for (int ni = 0; ni < 3; ++ni) {
      const int col = n0 + wn + ni * 16 + l15;
      if (col < 2560) {
        const bool isQ = (col < 2048);
        u16* dst = isQ ? qb : kb;
        const int ncol0 = isQ ? 0 : 2048;
        const int ndim  = isQ ? EQ_ : EK_;
        const float scale = isQ ? QSCALE : 1.0f;
        const int ip = (col & 63) >> 1;
        #pragma unroll
        for (int r = 0; r < 4; ++r) {
          int row = m0 + wm + mi * 16 + quad * 4 + r;
          const float* fr = fc + (size_t)(row & (S_ - 1)) * 64;
          float c  = fr[ip * 2];
          float sn = fr[ip * 2 + 1];
          float v = acc[mi][ni][r];
          float p = __shfl_xor(v, 1, 64);
          float o = (v * c + sg * (p * sn)) * scale;
          dst[(size_t)row * ndim + col - ncol0] = f2bf(o);
        }
      } else {
        const int vcol = col - 2560;
        uint2 w;
        w.x = pk2(acc[mi][ni][0], acc[mi][ni][1]);
        w.y = pk2(acc[mi][ni][2], acc[mi][ni][3]);
        *(uint2*)(vtb + (size_t)vcol * M_ + m0 + wm + mi * 16 + quad * 4) = w;
      }
    }
  }
}

// ---------------- O-projection GEMM v3 (R14): 128x128 tile, BK=32 dbuf ----------------
__global__ __launch_bounds__(256)
void gemm_o(const u16* __restrict__ A, const u16* __restrict__ Bw, float* __restrict__ C,
            int Ndim, int Kdim) {
  __shared__ __align__(16) u16 As[2][128 * 32];   // 2 x 8 KB
  __shared__ __align__(16) u16 Bs[2][128 * 32];   // 2 x 8 KB
  const int tid  = threadIdx.x;
  const int lane = tid & 63;
  const int wave = tid >> 6;
  const int m0 = blockIdx.y * 128;
  const int n0 = blockIdx.x * 128;
  const int wm = (wave >> 1) * 64;
  const int wn = (wave & 1) * 64;
  const int l15 = lane & 15;
  const int quad = lane >> 4;

  const int ca0 = tid,       ra0 = ca0 >> 2, pa0 = ca0 & 3;
  const int ca1 = tid + 256, ra1 = ca1 >> 2, pa1 = ca1 & 3;
  const u16* Ap0 = A + (size_t)(m0 + ra0) * Kdim + (pa0 ^ ((ra0 >> 1) & 3)) * 8;
  const u16* Ap1 = A + (size_t)(m0 + ra1) * Kdim + (pa1 ^ ((ra1 >> 1) & 3)) * 8;
  const u16* Bp0 = Bw + (size_t)(n0 + ra0) * Kdim + (pa0 ^ ((ra0 >> 1) & 3)) * 8;
  const u16* Bp1 = Bw + (size_t)(n0 + ra1) * Kdim + (pa1 ^ ((ra1 >> 1) & 3)) * 8;

  f32x4 acc[4][4] = {};

  const int nsteps = Kdim >> 5;

  gl_lds16(Ap0, &As[0][ca0 * 8]);
  gl_lds16(Ap1, &As[0][ca1 * 8]);
  gl_lds16(Bp0, &Bs[0][ca0 * 8]);
  gl_lds16(Bp1, &Bs[0][ca1 * 8]);
  __syncthreads();

  for (int ks = 0; ks < nsteps; ++ks) {
    if (ks + 1 < nsteps) {
      const int nb = (ks + 1) & 1;
      const int ko = (ks + 1) * 32;
      gl_lds16(Ap0 + ko, &As[nb][ca0 * 8]);
      gl_lds16(Ap1 + ko, &As[nb][ca1 * 8]);
      gl_lds16(Bp0 + ko, &Bs[nb][ca0 * 8]);
      gl_lds16(Bp1 + ko, &Bs[nb][ca1 * 8]);
    }

    const u16* as = &As[ks & 1][0];
    const u16* bs = &Bs[ks & 1][0];
    s16x8 af[4], bfr[4];
    #pragma unroll
    for (int mi = 0; mi < 4; ++mi) {
      int row = wm + mi * 16 + l15;
      af[mi] = *(const s16x8*)&as[row * 32 + (quad ^ ((row >> 1) & 3)) * 8];
    }
    #pragma unroll
    for (int ni = 0; ni < 4; ++ni) {
      int row = wn + ni * 16 + l15;
      bfr[ni] = *(const s16x8*)&bs[row * 32 + (quad ^ ((row >> 1) & 3)) * 8];
    }
    #pragma unroll
    for (int mi = 0; mi < 4; ++mi)
      #pragma unroll
      for (int ni = 0; ni < 4; ++ni)
        acc[mi][ni] = mfma16(af[mi], bfr[ni], acc[mi][ni]);

    __syncthreads();
  }

  #pragma unroll
  for (int mi = 0; mi < 4; ++mi) {
    #pragma unroll
    for (int r = 0; r < 4; ++r) {
      int row = m0 + wm + mi * 16 + quad * 4 + r;
      size_t base = (size_t)row * Ndim + n0 + wn;
      #pragma unroll
      for (int ni = 0; ni < 4; ++ni)
        C[base + ni * 16 + l15] = acc[mi][ni][r];
    }
  }
}

// QK^T pass: scores -> mask -> exp2 -> pack to PV B-operand layout (in-reg)
__device__ __forceinline__ void qk_pass(const s16x8* kk0, const s16x8* kk1,
                                        s16x8 q0, s16x8 q1, bool msk, int rowX,
                                        int t0, int quad, float& sum,
                                        s16x8& p0v, s16x8& p1v) {
  union PU { s16x8 v; unsigned u[4]; };
  f32x4 sS[4];
  #pragma unroll
  for (int ts = 0; ts < 4; ++ts) {
    f32x4 s = {};
    s = mfma16(kk0[ts], q0, s);
    s = mfma16(kk1[ts], q1, s);
    sS[ts] = s;
  }
  if (msk) {
    #pragma unroll
    for (int ts = 0; ts < 4; ++ts) {
      const int tb = t0 + ((ts & 2) << 4) + ((ts & 1) << 2) + quad * 8;
      #pragma unroll
      for (int r = 0; r < 4; ++r) if (tb + r > rowX) sS[ts][r] = -1e30f;
    }
  }
  float e[16];
  #pragma unroll
  for (int ts = 0; ts < 4; ++ts)
    #pragma unroll
    for (int r = 0; r < 4; ++r) {
      float x = EXP2(sS[ts][r] - EXPOFF);
      e[ts * 4 + r] = x;
      sum += x;
    }
  PU p0u, p1u;
  p0u.u[0] = pk2(e[0],  e[1]);  p0u.u[1] = pk2(e[2],  e[3]);
  p0u.u[2] = pk2(e[4],  e[5]);  p0u.u[3] = pk2(e[6],  e[7]);
  p1u.u[0] = pk2(e[8],  e[9]);  p1u.u[1] = pk2(e[10], e[11]);
  p1u.u[2] = pk2(e[12], e[13]); p1u.u[3] = pk2(e[14], e[15]);
  p0v = p0u.v; p1v = p1u.v;
}

// ---------------- causal GQA flash attention v10+T5 (R13-proven, unchanged) ----------------
__global__ __launch_bounds__(256, 2)
void flash_attn(const u16* __restrict__ qb, const u16* __restrict__ kb,
                const u16* __restrict__ vtb, u16* __restrict__ ob) {
  const int bx = blockIdx.x;        // 0..15
  const int hy = blockIdx.y;        // 0..15 -> heads 2hy, 2hy+1
  const int b  = blockIdx.z;
  const int h0 = hy * 2;
  const int g  = hy >> 1;           // shared KV group (REP=4)
  const int tid  = threadIdx.x;
  const int lane = tid & 63;
  const int wave = tid >> 6;
  const int l15  = lane & 15;
  const int quad = lane >> 4;
  const int kq   = quad * 8;

  const int Tlo = bx, Thi = 31 - bx;
  const int n_lo = Tlo + 1, n_hi = Thi + 1;
  const int rL = Tlo * 64 + wave * 16;
  const int rH = Thi * 64 + wave * 16;
  const int rowL = rL + l15;
  const int rowH = rH + l15;

  __shared__ __align__(16) u16 Ks[2][8 * 512];   // 16 KB
  __shared__ __align__(16) u16 Vs[2][8 * 512];   // 16 KB  (total 32 KB)

  // Q fragments: rows (H,L) x heads (h0, h0+1), 2 halves of HD each
  const u16* qpH0 = qb + (size_t)(b * S_ + rH + l15) * EQ_ + h0 * HD_;
  const u16* qpL0 = qb + (size_t)(b * S_ + rL + l15) * EQ_ + h0 * HD_;
  s16x8 qHa0 = *(const s16x8*)(qpH0 + kq);
  s16x8 qHa1 = *(const s16x8*)(qpH0 + 32 + kq);
  s16x8 qHb0 = *(const s16x8*)(qpH0 + HD_ + kq);
  s16x8 qHb1 = *(const s16x8*)(qpH0 + HD_ + 32 + kq);
  s16x8 qLa0 = *(const s16x8*)(qpL0 + kq);
  s16x8 qLa1 = *(const s16x8*)(qpL0 + 32 + kq);
  s16x8 qLb0 = *(const s16x8*)(qpL0 + HD_ + kq);
  s16x8 qLb1 = *(const s16x8*)(qpL0 + HD_ + 32 + kq);

  f32x4 OHa[4] = {}, OHb[4] = {}, OLa[4] = {}, OLb[4] = {};
  float sumHa = 0.f, sumHb = 0.f, sumLa = 0.f, sumLb = 0.f;

  const int sw = wave & 1;
  const bool doK = (wave < 2);

  // K row bit-permutation for staging (v9-proven): LDS row p holds global
  // row t(p) = b5*32 + (b3b2)*8 + b4*4 + b1b0.
  const int tl = (lane & 0x23) | ((lane & 0x0C) << 1) | ((lane & 0x10) >> 2);

  const u16* stbase;
  size_t     tstride;
  if (doK) {
    stbase  = kb + (size_t)(b * S_ + tl) * EK_ + g * HD_ + sw * 32;
    tstride = (size_t)64 * EK_;
  } else {
    stbase  = vtb + (size_t)(g * HD_ + lane) * M_ + b * S_ + sw * 32;
    tstride = 64;
  }
  const int ldoff = sw * 4 * 512 + lane * 8;
  u16* mybuf0 = (doK ? &Ks[0][0] : &Vs[0][0]) + ldoff;
  u16* mybuf1 = (doK ? &Ks[1][0] : &Vs[1][0]) + ldoff;

  // prologue: stage tile 0 (K and V) into buffer 0
  #pragma unroll
  for (int r = 0; r < 4; ++r)
    gl_lds16(stbase + r * 8, mybuf0 + r * 512);
  __syncthreads();

  for (int kt = 0; kt < n_hi; ++kt) {
    const int t0 = kt * 64;
    const u16* kcur = &Ks[kt & 1][0];
    const u16* vcur = &Vs[kt & 1][0];

    if (kt + 1 < n_hi) {
      const u16* src = stbase + (size_t)(kt + 1) * tstride;
      u16* dst = ((kt + 1) & 1) ? mybuf1 : mybuf0;
      #pragma unroll
      for (int r = 0; r < 4; ++r)
        gl_lds16(src + r * 8, dst + r * 512);
    }

    const bool do_lo = (kt < n_lo);
    const bool mH = (kt == n_hi - 1);
    const bool mL = (kt == n_lo - 1);

    // ---- T5: prioritize this wave through its MFMA-dense compute section ----
    __builtin_amdgcn_s_setprio(1);

    s16x8 kk0[4], kk1[4];
    #pragma unroll
    for (int ts = 0; ts < 4; ++ts) {
      kk0[ts] = *(const s16x8*)&kcur[quad * 512 + (ts * 16 + l15) * 8];
      kk1[ts] = *(const s16x8*)&kcur[(4 + quad) * 512 + (ts * 16 + l15) * 8];
    }

    // ---- 4 softmax passes, all in-register ----
    s16x8 pHa0, pHa1, pHb0, pHb1, pLa0, pLa1, pLb0, pLb1;
    qk_pass(kk0, kk1, qHa0, qHa1, mH, rowH, t0, quad, sumHa, pHa0, pHa1);
    qk_pass(kk0, kk1, qHb0, qHb1, mH, rowH, t0, quad, sumHb, pHb0, pHb1);
    if (do_lo) {
      qk_pass(kk0, kk1, qLa0, qLa1, mL, rowL, t0, quad, sumLa, pLa0, pLa1);
      qk_pass(kk0, kk1, qLb0, qLb1, mL, rowL, t0, quad, sumLb, pLb0, pLb1);
    } else {
      pLa0 = s16x8{}; pLa1 = s16x8{}; pLb0 = s16x8{}; pLb1 = s16x8{};
    }

    // ---- PV: one V read pair serves 8 MFMAs ----
    #pragma unroll
    for (int df = 0; df < 4; ++df) {
      s16x8 v0 = *(const s16x8*)&vcur[quad * 512 + (df * 16 + l15) * 8];
      s16x8 v1 = *(const s16x8*)&vcur[(4 + quad) * 512 + (df * 16 + l15) * 8];
      OHa[df] = mfma16(v1, pHa1, mfma16(v0, pHa0, OHa[df]));
      OHb[df] = mfma16(v1, pHb1, mfma16(v0, pHb0, OHb[df]));
      if (do_lo) {
        OLa[df] = mfma16(v1, pLa1, mfma16(v0, pLa0, OLa[df]));
        OLb[df] = mfma16(v1, pLb1, mfma16(v0, pLb0, OLb[df]));
      }
    }

    __builtin_amdgcn_s_setprio(0);
    __syncthreads();
  }

  sumHa += __shfl_xor(sumHa, 16, 64); sumHa += __shfl_xor(sumHa, 32, 64);
  sumHb += __shfl_xor(sumHb, 16, 64); sumHb += __shfl_xor(sumHb, 32, 64);
  sumLa += __shfl_xor(sumLa, 16, 64); sumLa += __shfl_xor(sumLa, 32, 64);
  sumLb += __shfl_xor(sumLb, 16, 64); sumLb += __shfl_xor(sumLb, 32, 64);
  float iHa = 1.f / sumHa, iHb = 1.f / sumHb;
  float iLa = 1.f / sumLa, iLb = 1.f / sumLb;

  {
    u16* op = ob + (size_t)(b * S_ + rowH) * EQ_ + h0 * HD_;
    #pragma unroll
    for (int df = 0; df < 4; ++df) {
      uint2 w;
      w.x = pk2(OHa[df][0] * iHa, OHa[df][1] * iHa);
      w.y = pk2(OHa[df][2] * iHa, OHa[df][3] * iHa);
      *(uint2*)(op + df * 16 + quad * 4) = w;
      uint2 w2;
      w2.x = pk2(OHb[df][0] * iHb, OHb[df][1] * iHb);
      w2.y = pk2(OHb[df][2] * iHb, OHb[df][3] * iHb);
      *(uint2*)(op + HD_ + df * 16 + quad * 4) = w2;
    }
  }
  {
    u16* op = ob + (size_t)(b * S_ + rowL) * EQ_ + h0 * HD_;
    #pragma unroll
    for (int df = 0; df < 4; ++df) {
      uint2 w;
      w.x = pk2(OLa[df][0] * iLa, OLa[df][1] * iLa);
      w.y = pk2(OLa[df][2] * iLa, OLa[df][3] * iLa);
      *(uint2*)(op + df * 16 + quad * 4) = w;
      uint2 w2;
      w2.x = pk2(OLb[df][0] * iLb, OLb[df][1] * iLb);
      w2.y = pk2(OLb[df][2] * iLb, OLb[df][3] * iLb);
      *(uint2*)(op + HD_ + df * 16 + quad * 4) = w2;
    }
  }
}

extern "C" void kernel_launch(void* const* d_in, const int* in_sizes, int n_in,
                              void* d_out, int out_size, void* d_ws, size_t ws_size,
                              hipStream_t stream) {
  (void)in_sizes; (void)n_in; (void)out_size; (void)ws_size;
  const float* x  = (const float*)d_in[0];
  const float* fc = (const float*)d_in[1];
  const float* wq = (const float*)d_in[2];
  const float* wk = (const float*)d_in[3];
  const float* wv = (const float*)d_in[4];
  const float* wo = (const float*)d_in[5];
  float* out = (float*)d_out;
  char* ws = (char*)d_ws;

  u16* xb  = (u16*)(ws);              // 4096x2048
  u16* wqb = (u16*)(ws + 16777216);   // 2048x2048  } contiguous fused [wq;wk;wv]
  u16* wob = (u16*)(ws + 29360128);   // 2048x2048
  u16* qb  = (u16*)(ws + 37748736);   // 4096x2048  (rope'd, x QSCALE)
  u16* kb  = (u16*)(ws + 54525952);   // 4096x512   (rope'd)
  u16* vtb = (u16*)(ws + 58720256);   // 512x4096   (V^T)
  u16* ob  = (u16*)(ws + 62914560);   // 4096x2048

  cast_all<<<2048, 256, 0, stream>>>((const float4*)x, (const float4*)wq,
                                     (const float4*)wk, (const float4*)wv,
                                     (const float4*)wo, (ushort4*)ws);

  gemm_qkv<<<dim3(32, 32), 256, 0, stream>>>(xb, wqb, qb, kb, vtb, fc);

  flash_attn<<<dim3(16, 16, 2), 256, 0, stream>>>(qb, kb, vtb, ob);

  gemm_o<<<dim3(16, 32), 256, 0, stream>>>(ob, wob, out, D_, EQ_);
}

// Round 16
// 275.886 us; speedup vs baseline: 1.1078x; 1.1078x over previous
//
#include <hip/hip_runtime.h>
#include <cstdint>
#include <cstddef>

#define B_ 2
#define S_ 2048
#define D_ 2048
#define H_ 32
#define KV_ 8
#define HD_ 64
#define M_ (B_*S_)      // 4096 rows total
#define EQ_ (H_*HD_)    // 2048
#define EK_ (KV_*HD_)   // 512

typedef unsigned short u16;
typedef __attribute__((ext_vector_type(8))) short s16x8;   // 8 x bf16 (4 VGPRs)
typedef __attribute__((ext_vector_type(4))) float f32x4;

// q pre-scale folds 1/sqrt(HD)=0.125 and log2(e) so flash uses raw 2^x
#define QSCALE 0.18033688011112042f      // 0.125 * log2(e)
#define EXPOFF 15.869645449778564f       // 11 * log2(e)

#if __has_builtin(__builtin_amdgcn_exp2f)
#define EXP2(x) __builtin_amdgcn_exp2f(x)
#else
#define EXP2(x) __expf((x) * 0.6931471805599453f)
#endif

__device__ __forceinline__ u16 f2bf(float f) {
  unsigned u = __float_as_uint(f);
  u += 0x7fffu + ((u >> 16) & 1u);        // RNE
  return (u16)(u >> 16);
}
// pack two floats to two bf16 in one dword via v_perm (proven path)
__device__ __forceinline__ unsigned pk2(float a, float b) {
  unsigned ua = __float_as_uint(a) + 0x8000u;
  unsigned ub = __float_as_uint(b) + 0x8000u;
  return __builtin_amdgcn_perm(ub, ua, 0x07060302);  // lo16=bf16(a), hi16=bf16(b)
}
__device__ __forceinline__ f32x4 mfma16(s16x8 a, s16x8 b, f32x4 c) {
  return __builtin_amdgcn_mfma_f32_16x16x32_bf16(a, b, c, 0, 0, 0);
}
__device__ __forceinline__ void gl_lds16(const void* g, void* l) {
  __builtin_amdgcn_global_load_lds(
      (const __attribute__((address_space(1))) void*)g,
      (__attribute__((address_space(3))) void*)l, 16, 0, 0);
}

// ---------------- fused fp32 -> bf16 cast of all 5 inputs ----------------
// Grid-stride (G11): 2048 blocks x 256 threads x 9 iters = 4718592 exact.
__global__ void cast_all(const float4* __restrict__ x, const float4* __restrict__ wq,
                         const float4* __restrict__ wk, const float4* __restrict__ wv,
                         const float4* __restrict__ wo, ushort4* __restrict__ dst) {
  for (int i = blockIdx.x * 256 + threadIdx.x; i < 4718592; i += 524288) {
    const float4* src; int off;
    if (i < 2097152)      { src = x;  off = i; }
    else if (i < 3145728) { src = wq; off = i - 2097152; }
    else if (i < 3407872) { src = wk; off = i - 3145728; }
    else if (i < 3670016) { src = wv; off = i - 3407872; }
    else                  { src = wo; off = i - 3670016; }
    float4 v = src[off];
    ushort4 r;
    r.x = f2bf(v.x); r.y = f2bf(v.y); r.z = f2bf(v.z); r.w = f2bf(v.w);
    dst[i] = r;
  }
}

// ---------------- fused QKV projection GEMM v2 + T1 XCD swizzle ----------------
// 128x96 tile, BK=32 double-buffered, issue-before-compute, 1 barrier/step
// (R4/R9-proven compute). NEW: 1D grid 1024 with bijective XCD swizzle
// swz = (bid&7)*128 + (bid>>3): each XCD owns 4 contiguous m-panels
// (A slice 2 MB -> L2-resident) across all n -> A re-reads become L2 hits,
// shortening the load latency the per-step barrier drains.
__global__ __launch_bounds__(256)
void gemm_qkv(const u16* __restrict__ A, const u16* __restrict__ Bw,
              u16* __restrict__ qb, u16* __restrict__ kb, u16* __restrict__ vtb,
              const float* __restrict__ fc) {
  __shared__ __align__(16) u16 As[2][128 * 32];   // 2 x 8 KB
  __shared__ __align__(16) u16 Bs[2][96 * 32];    // 2 x 6 KB
  const int tid  = threadIdx.x;
  const int lane = tid & 63;
  const int wave = tid >> 6;
  const int swz  = (blockIdx.x & 7) * 128 + (blockIdx.x >> 3);  // bijective, 1024=8x128
  const int m0 = (swz >> 5) * 128;    // m-block 0..31
  const int n0 = (swz & 31) * 96;     // n-block 0..31
  const int wm = (wave >> 1) * 64;
  const int wn = (wave & 1) * 48;
  const int l15 = lane & 15;
  const int quad = lane >> 4;

  const int ca0 = tid,      ra0 = ca0 >> 2, pa0 = ca0 & 3;
  const int ca1 = tid + 256, ra1 = ca1 >> 2, pa1 = ca1 & 3;
  const int cb0 = tid,      rb0 = cb0 >> 2, pb0 = cb0 & 3;
  const int cb1 = tid + 256, rb1 = cb1 >> 2, pb1 = cb1 & 3;
  const u16* Ap0 = A + (size_t)(m0 + ra0) * D_ + (pa0 ^ ((ra0 >> 1) & 3)) * 8;
  const u16* Ap1 = A + (size_t)(m0 + ra1) * D_ + (pa1 ^ ((ra1 >> 1) & 3)) * 8;
  const u16* Bp0 = Bw + (size_t)(n0 + rb0) * D_ + (pb0 ^ ((rb0 >> 1) & 3)) * 8;
  const u16* Bp1 = Bw + (size_t)(n0 + rb1) * D_ + (pb1 ^ ((rb1 >> 1) & 3)) * 8;
  const bool doB1 = (tid < 128);

  f32x4 acc[4][3] = {};

  gl_lds16(Ap0, &As[0][ca0 * 8]);
  gl_lds16(Ap1, &As[0][ca1 * 8]);
  gl_lds16(Bp0, &Bs[0][cb0 * 8]);
  if (doB1) gl_lds16(Bp1, &Bs[0][cb1 * 8]);
  __syncthreads();

  for (int ks = 0; ks < 64; ++ks) {
    if (ks + 1 < 64) {
      const int nb = (ks + 1) & 1;
      const int ko = (ks + 1) * 32;
      gl_lds16(Ap0 + ko, &As[nb][ca0 * 8]);
      gl_lds16(Ap1 + ko, &As[nb][ca1 * 8]);
      gl_lds16(Bp0 + ko, &Bs[nb][cb0 * 8]);
      if (doB1) gl_lds16(Bp1 + ko, &Bs[nb][cb1 * 8]);
    }

    const u16* as = &As[ks & 1][0];
    const u16* bs = &Bs[ks & 1][0];
    s16x8 af[4], bfr[3];
    #pragma unroll
    for (int mi = 0; mi < 4; ++mi) {
      int row = wm + mi * 16 + l15;
      af[mi] = *(const s16x8*)&as[row * 32 + (quad ^ ((row >> 1) & 3)) * 8];
    }
    #pragma unroll
    for (int ni = 0; ni < 3; ++ni) {
      int row = wn + ni * 16 + l15;
      bfr[ni] = *(const s16x8*)&bs[row * 32 + (quad ^ ((row >> 1) & 3)) * 8];
    }
    #pragma unroll
    for (int mi = 0; mi < 4; ++mi)
      #pragma unroll
      for (int ni = 0; ni < 3; ++ni)
        acc[mi][ni] = mfma16(af[mi], bfr[ni], acc[mi][ni]);

    __syncthreads();
  }

  // ---- epilogue: per-ni region branch (wave-uniform) ----
  const float sg = (l15 & 1) ? 1.f : -1.f;
  #pragma unroll
  for (int mi = 0; mi < 4; ++mi) {
    #pragma unroll
    for (int ni = 0; ni < 3; ++ni) {
      const int col = n0 + wn + ni * 16 + l15;
      if (col < 2560) {
        const bool isQ = (col < 2048);
        u16* dst = isQ ? qb : kb;
        const int ncol0 = isQ ? 0 : 2048;
        const int ndim  = isQ ? EQ_ : EK_;
        const float scale = isQ ? QSCALE : 1.0f;
        const int ip = (col & 63) >> 1;
        #pragma unroll
        for (int r = 0; r < 4; ++r) {
          int row = m0 + wm + mi * 16 + quad * 4 + r;
          const float* fr = fc + (size_t)(row & (S_ - 1)) * 64;
          float c  = fr[ip * 2];
          float sn = fr[ip * 2 + 1];
          float v = acc[mi][ni][r];
          float p = __shfl_xor(v, 1, 64);
          float o = (v * c + sg * (p * sn)) * scale;
          dst[(size_t)row * ndim + col - ncol0] = f2bf(o);
        }
      } else {
        const int vcol = col - 2560;
        uint2 w;
        w.x = pk2(acc[mi][ni][0], acc[mi][ni][1]);
        w.y = pk2(acc[mi][ni][2], acc[mi][ni][3]);
        *(uint2*)(vtb + (size_t)vcol * M_ + m0 + wm + mi * 16 + quad * 4) = w;
      }
    }
  }
}

// ---------------- O-projection GEMM v3 + T1 XCD swizzle: 128x128, BK=32 dbuf ----------------
// swz = (bid&7)*64 + (bid>>3) (512 = 8x64 bijective): each XCD owns 4
// contiguous m-panels (A slice 1 MB, L2-resident) across all n.
__global__ __launch_bounds__(256)
void gemm_o(const u16* __restrict__ A, const u16* __restrict__ Bw, float* __restrict__ C,
            int Ndim, int Kdim) {
  __shared__ __align__(16) u16 As[2][128 * 32];   // 2 x 8 KB
  __shared__ __align__(16) u16 Bs[2][128 * 32];   // 2 x 8 KB
  const int tid  = threadIdx.x;
  const int lane = tid & 63;
  const int wave = tid >> 6;
  const int swz  = (blockIdx.x & 7) * 64 + (blockIdx.x >> 3);   // bijective, 512=8x64
  const int m0 = (swz >> 4) * 128;    // m-block 0..31
  const int n0 = (swz & 15) * 128;    // n-block 0..15
  const int wm = (wave >> 1) * 64;
  const int wn = (wave & 1) * 64;
  const int l15 = lane & 15;
  const int quad = lane >> 4;

  const int ca0 = tid,       ra0 = ca0 >> 2, pa0 = ca0 & 3;
  const int ca1 = tid + 256, ra1 = ca1 >> 2, pa1 = ca1 & 3;
  const u16* Ap0 = A + (size_t)(m0 + ra0) * Kdim + (pa0 ^ ((ra0 >> 1) & 3)) * 8;
  const u16* Ap1 = A + (size_t)(m0 + ra1) * Kdim + (pa1 ^ ((ra1 >> 1) & 3)) * 8;
  const u16* Bp0 = Bw + (size_t)(n0 + ra0) * Kdim + (pa0 ^ ((ra0 >> 1) & 3)) * 8;
  const u16* Bp1 = Bw + (size_t)(n0 + ra1) * Kdim + (pa1 ^ ((ra1 >> 1) & 3)) * 8;

  f32x4 acc[4][4] = {};

  const int nsteps = Kdim >> 5;

  gl_lds16(Ap0, &As[0][ca0 * 8]);
  gl_lds16(Ap1, &As[0][ca1 * 8]);
  gl_lds16(Bp0, &Bs[0][ca0 * 8]);
  gl_lds16(Bp1, &Bs[0][ca1 * 8]);
  __syncthreads();

  for (int ks = 0; ks < nsteps; ++ks) {
    if (ks + 1 < nsteps) {
      const int nb = (ks + 1) & 1;
      const int ko = (ks + 1) * 32;
      gl_lds16(Ap0 + ko, &As[nb][ca0 * 8]);
      gl_lds16(Ap1 + ko, &As[nb][ca1 * 8]);
      gl_lds16(Bp0 + ko, &Bs[nb][ca0 * 8]);
      gl_lds16(Bp1 + ko, &Bs[nb][ca1 * 8]);
    }

    const u16* as = &As[ks & 1][0];
    const u16* bs = &Bs[ks & 1][0];
    s16x8 af[4], bfr[4];
    #pragma unroll
    for (int mi = 0; mi < 4; ++mi) {
      int row = wm + mi * 16 + l15;
      af[mi] = *(const s16x8*)&as[row * 32 + (quad ^ ((row >> 1) & 3)) * 8];
    }
    #pragma unroll
    for (int ni = 0; ni < 4; ++ni) {
      int row = wn + ni * 16 + l15;
      bfr[ni] = *(const s16x8*)&bs[row * 32 + (quad ^ ((row >> 1) & 3)) * 8];
    }
    #pragma unroll
    for (int mi = 0; mi < 4; ++mi)
      #pragma unroll
      for (int ni = 0; ni < 4; ++ni)
        acc[mi][ni] = mfma16(af[mi], bfr[ni], acc[mi][ni]);

    __syncthreads();
  }

  #pragma unroll
  for (int mi = 0; mi < 4; ++mi) {
    #pragma unroll
    for (int r = 0; r < 4; ++r) {
      int row = m0 + wm + mi * 16 + quad * 4 + r;
      size_t base = (size_t)row * Ndim + n0 + wn;
      #pragma unroll
      for (int ni = 0; ni < 4; ++ni)
        C[base + ni * 16 + l15] = acc[mi][ni][r];
    }
  }
}

// QK^T pass: scores -> mask -> exp2 -> pack to PV B-operand layout (in-reg)
__device__ __forceinline__ void qk_pass(const s16x8* kk0, const s16x8* kk1,
                                        s16x8 q0, s16x8 q1, bool msk, int rowX,
                                        int t0, int quad, float& sum,
                                        s16x8& p0v, s16x8& p1v) {
  union PU { s16x8 v; unsigned u[4]; };
  f32x4 sS[4];
  #pragma unroll
  for (int ts = 0; ts < 4; ++ts) {
    f32x4 s = {};
    s = mfma16(kk0[ts], q0, s);
    s = mfma16(kk1[ts], q1, s);
    sS[ts] = s;
  }
  if (msk) {
    #pragma unroll
    for (int ts = 0; ts < 4; ++ts) {
      const int tb = t0 + ((ts & 2) << 4) + ((ts & 1) << 2) + quad * 8;
      #pragma unroll
      for (int r = 0; r < 4; ++r) if (tb + r > rowX) sS[ts][r] = -1e30f;
    }
  }
  float e[16];
  #pragma unroll
  for (int ts = 0; ts < 4; ++ts)
    #pragma unroll
    for (int r = 0; r < 4; ++r) {
      float x = EXP2(sS[ts][r] - EXPOFF);
      e[ts * 4 + r] = x;
      sum += x;
    }
  PU p0u, p1u;
  p0u.u[0] = pk2(e[0],  e[1]);  p0u.u[1] = pk2(e[2],  e[3]);
  p0u.u[2] = pk2(e[4],  e[5]);  p0u.u[3] = pk2(e[6],  e[7]);
  p1u.u[0] = pk2(e[8],  e[9]);  p1u.u[1] = pk2(e[10], e[11]);
  p1u.u[2] = pk2(e[12], e[13]); p1u.u[3] = pk2(e[14], e[15]);
  p0v = p0u.v; p1v = p1u.v;
}

// ---------------- causal GQA flash attention v10+T5 (R13-proven, unchanged) ----------------
__global__ __launch_bounds__(256, 2)
void flash_attn(const u16* __restrict__ qb, const u16* __restrict__ kb,
                const u16* __restrict__ vtb, u16* __restrict__ ob) {
  const int bx = blockIdx.x;        // 0..15
  const int hy = blockIdx.y;        // 0..15 -> heads 2hy, 2hy+1
  const int b  = blockIdx.z;
  const int h0 = hy * 2;
  const int g  = hy >> 1;           // shared KV group (REP=4)
  const int tid  = threadIdx.x;
  const int lane = tid & 63;
  const int wave = tid >> 6;
  const int l15  = lane & 15;
  const int quad = lane >> 4;
  const int kq   = quad * 8;

  const int Tlo = bx, Thi = 31 - bx;
  const int n_lo = Tlo + 1, n_hi = Thi + 1;
  const int rL = Tlo * 64 + wave * 16;
  const int rH = Thi * 64 + wave * 16;
  const int rowL = rL + l15;
  const int rowH = rH + l15;

  __shared__ __align__(16) u16 Ks[2][8 * 512];   // 16 KB
  __shared__ __align__(16) u16 Vs[2][8 * 512];   // 16 KB  (total 32 KB)

  // Q fragments: rows (H,L) x heads (h0, h0+1), 2 halves of HD each
  const u16* qpH0 = qb + (size_t)(b * S_ + rH + l15) * EQ_ + h0 * HD_;
  const u16* qpL0 = qb + (size_t)(b * S_ + rL + l15) * EQ_ + h0 * HD_;
  s16x8 qHa0 = *(const s16x8*)(qpH0 + kq);
  s16x8 qHa1 = *(const s16x8*)(qpH0 + 32 + kq);
  s16x8 qHb0 = *(const s16x8*)(qpH0 + HD_ + kq);
  s16x8 qHb1 = *(const s16x8*)(qpH0 + HD_ + 32 + kq);
  s16x8 qLa0 = *(const s16x8*)(qpL0 + kq);
  s16x8 qLa1 = *(const s16x8*)(qpL0 + 32 + kq);
  s16x8 qLb0 = *(const s16x8*)(qpL0 + HD_ + kq);
  s16x8 qLb1 = *(const s16x8*)(qpL0 + HD_ + 32 + kq);

  f32x4 OHa[4] = {}, OHb[4] = {}, OLa[4] = {}, OLb[4] = {};
  float sumHa = 0.f, sumHb = 0.f, sumLa = 0.f, sumLb = 0.f;

  const int sw = wave & 1;
  const bool doK = (wave < 2);

  // K row bit-permutation for staging (v9-proven): LDS row p holds global
  // row t(p) = b5*32 + (b3b2)*8 + b4*4 + b1b0.
  const int tl = (lane & 0x23) | ((lane & 0x0C) << 1) | ((lane & 0x10) >> 2);

  const u16* stbase;
  size_t     tstride;
  if (doK) {
    stbase  = kb + (size_t)(b * S_ + tl) * EK_ + g * HD_ + sw * 32;
    tstride = (size_t)64 * EK_;
  } else {
    stbase  = vtb + (size_t)(g * HD_ + lane) * M_ + b * S_ + sw * 32;
    tstride = 64;
  }
  const int ldoff = sw * 4 * 512 + lane * 8;
  u16* mybuf0 = (doK ? &Ks[0][0] : &Vs[0][0]) + ldoff;
  u16* mybuf1 = (doK ? &Ks[1][0] : &Vs[1][0]) + ldoff;

  // prologue: stage tile 0 (K and V) into buffer 0
  #pragma unroll
  for (int r = 0; r < 4; ++r)
    gl_lds16(stbase + r * 8, mybuf0 + r * 512);
  __syncthreads();

  for (int kt = 0; kt < n_hi; ++kt) {
    const int t0 = kt * 64;
    const u16* kcur = &Ks[kt & 1][0];
    const u16* vcur = &Vs[kt & 1][0];

    if (kt + 1 < n_hi) {
      const u16* src = stbase + (size_t)(kt + 1) * tstride;
      u16* dst = ((kt + 1) & 1) ? mybuf1 : mybuf0;
      #pragma unroll
      for (int r = 0; r < 4; ++r)
        gl_lds16(src + r * 8, dst + r * 512);
    }

    const bool do_lo = (kt < n_lo);
    const bool mH = (kt == n_hi - 1);
    const bool mL = (kt == n_lo - 1);

    // ---- T5: prioritize this wave through its MFMA-dense compute section ----
    __builtin_amdgcn_s_setprio(1);

    s16x8 kk0[4], kk1[4];
    #pragma unroll
    for (int ts = 0; ts < 4; ++ts) {
      kk0[ts] = *(const s16x8*)&kcur[quad * 512 + (ts * 16 + l15) * 8];
      kk1[ts] = *(const s16x8*)&kcur[(4 + quad) * 512 + (ts * 16 + l15) * 8];
    }

    // ---- 4 softmax passes, all in-register ----
    s16x8 pHa0, pHa1, pHb0, pHb1, pLa0, pLa1, pLb0, pLb1;
    qk_pass(kk0, kk1, qHa0, qHa1, mH, rowH, t0, quad, sumHa, pHa0, pHa1);
    qk_pass(kk0, kk1, qHb0, qHb1, mH, rowH, t0, quad, sumHb, pHb0, pHb1);
    if (do_lo) {
      qk_pass(kk0, kk1, qLa0, qLa1, mL, rowL, t0, quad, sumLa, pLa0, pLa1);
      qk_pass(kk0, kk1, qLb0, qLb1, mL, rowL, t0, quad, sumLb, pLb0, pLb1);
    } else {
      pLa0 = s16x8{}; pLa1 = s16x8{}; pLb0 = s16x8{}; pLb1 = s16x8{};
    }

    // ---- PV: one V read pair serves 8 MFMAs ----
    #pragma unroll
    for (int df = 0; df < 4; ++df) {
      s16x8 v0 = *(const s16x8*)&vcur[quad * 512 + (df * 16 + l15) * 8];
      s16x8 v1 = *(const s16x8*)&vcur[(4 + quad) * 512 + (df * 16 + l15) * 8];
      OHa[df] = mfma16(v1, pHa1, mfma16(v0, pHa0, OHa[df]));
      OHb[df] = mfma16(v1, pHb1, mfma16(v0, pHb0, OHb[df]));
      if (do_lo) {
        OLa[df] = mfma16(v1, pLa1, mfma16(v0, pLa0, OLa[df]));
        OLb[df] = mfma16(v1, pLb1, mfma16(v0, pLb0, OLb[df]));
      }
    }

    __builtin_amdgcn_s_setprio(0);
    __syncthreads();
  }

  sumHa += __shfl_xor(sumHa, 16, 64); sumHa += __shfl_xor(sumHa, 32, 64);
  sumHb += __shfl_xor(sumHb, 16, 64); sumHb += __shfl_xor(sumHb, 32, 64);
  sumLa += __shfl_xor(sumLa, 16, 64); sumLa += __shfl_xor(sumLa, 32, 64);
  sumLb += __shfl_xor(sumLb, 16, 64); sumLb += __shfl_xor(sumLb, 32, 64);
  float iHa = 1.f / sumHa, iHb = 1.f / sumHb;
  float iLa = 1.f / sumLa, iLb = 1.f / sumLb;

  {
    u16* op = ob + (size_t)(b * S_ + rowH) * EQ_ + h0 * HD_;
    #pragma unroll
    for (int df = 0; df < 4; ++df) {
      uint2 w;
      w.x = pk2(OHa[df][0] * iHa, OHa[df][1] * iHa);
      w.y = pk2(OHa[df][2] * iHa, OHa[df][3] * iHa);
      *(uint2*)(op + df * 16 + quad * 4) = w;
      uint2 w2;
      w2.x = pk2(OHb[df][0] * iHb, OHb[df][1] * iHb);
      w2.y = pk2(OHb[df][2] * iHb, OHb[df][3] * iHb);
      *(uint2*)(op + HD_ + df * 16 + quad * 4) = w2;
    }
  }
  {
    u16* op = ob + (size_t)(b * S_ + rowL) * EQ_ + h0 * HD_;
    #pragma unroll
    for (int df = 0; df < 4; ++df) {
      uint2 w;
      w.x = pk2(OLa[df][0] * iLa, OLa[df][1] * iLa);
      w.y = pk2(OLa[df][2] * iLa, OLa[df][3] * iLa);
      *(uint2*)(op + df * 16 + quad * 4) = w;
      uint2 w2;
      w2.x = pk2(OLb[df][0] * iLb, OLb[df][1] * iLb);
      w2.y = pk2(OLb[df][2] * iLb, OLb[df][3] * iLb);
      *(uint2*)(op + HD_ + df * 16 + quad * 4) = w2;
    }
  }
}

extern "C" void kernel_launch(void* const* d_in, const int* in_sizes, int n_in,
                              void* d_out, int out_size, void* d_ws, size_t ws_size,
                              hipStream_t stream) {
  (void)in_sizes; (void)n_in; (void)out_size; (void)ws_size;
  const float* x  = (const float*)d_in[0];
  const float* fc = (const float*)d_in[1];
  const float* wq = (const float*)d_in[2];
  const float* wk = (const float*)d_in[3];
  const float* wv = (const float*)d_in[4];
  const float* wo = (const float*)d_in[5];
  float* out = (float*)d_out;
  char* ws = (char*)d_ws;

  u16* xb  = (u16*)(ws);              // 4096x2048
  u16* wqb = (u16*)(ws + 16777216);   // 2048x2048  } contiguous fused [wq;wk;wv]
  u16* wob = (u16*)(ws + 29360128);   // 2048x2048
  u16* qb  = (u16*)(ws + 37748736);   // 4096x2048  (rope'd, x QSCALE)
  u16* kb  = (u16*)(ws + 54525952);   // 4096x512   (rope'd)
  u16* vtb = (u16*)(ws + 58720256);   // 512x4096   (V^T)
  u16* ob  = (u16*)(ws + 62914560);   // 4096x2048

  cast_all<<<2048, 256, 0, stream>>>((const float4*)x, (const float4*)wq,
                                     (const float4*)wk, (const float4*)wv,
                                     (const float4*)wo, (ushort4*)ws);

  gemm_qkv<<<1024, 256, 0, stream>>>(xb, wqb, qb, kb, vtb, fc);

  flash_attn<<<dim3(16, 16, 2), 256, 0, stream>>>(qb, kb, vtb, ob);

  gemm_o<<<512, 256, 0, stream>>>(ob, wob, out, D_, EQ_);
}